// Round 2
// baseline (98.389 us; speedup 1.0000x reference)
//
#include <hip/hip_runtime.h>
#include <hip/hip_bf16.h>

#define N_CLASSES 256
#define DIM 128
#define M_ROWS 8192
#define S_ROWS 4096

#define MT 32    // m-rows per block (dist kernel)
#define NT 128   // classes per block (dist kernel)

typedef short  bf16x8  __attribute__((ext_vector_type(8)));
typedef unsigned short ushort8 __attribute__((ext_vector_type(8)));
typedef float  f32x4   __attribute__((ext_vector_type(4)));

// ---------------- prototypes: per-class mean, output bf16 ----------------
// 32 blocks; block b owns dims [4b, 4b+4). LDS-accumulated sums+counts,
// every proto element written exactly once -> no pre-zero, no global atomics.
__global__ __launch_bounds__(512) void proto_kernel(
    const float* __restrict__ support, const int* __restrict__ labels,
    __hip_bfloat16* __restrict__ proto /* [256][128] */)
{
    __shared__ float lsum[N_CLASSES][4];
    __shared__ float lcnt[N_CLASSES];

    const int t = threadIdx.x;        // 0..511
    const int b = blockIdx.x;         // dim-slice 4b..4b+3

    #pragma unroll
    for (int i = t; i < N_CLASSES * 4; i += 512) ((float*)lsum)[i] = 0.0f;
    if (t < N_CLASSES) lcnt[t] = 0.0f;
    __syncthreads();

    #pragma unroll
    for (int it = 0; it < S_ROWS / 512; ++it) {   // 8 iters
        int r = it * 512 + t;
        int lab = labels[r];
        float4 v = *reinterpret_cast<const float4*>(support + (size_t)r * DIM + b * 4);
        atomicAdd(&lsum[lab][0], v.x);
        atomicAdd(&lsum[lab][1], v.y);
        atomicAdd(&lsum[lab][2], v.z);
        atomicAdd(&lsum[lab][3], v.w);
        atomicAdd(&lcnt[lab], 1.0f);
    }
    __syncthreads();

    if (t < N_CLASSES) {
        float inv = 1.0f / fmaxf(lcnt[t], 1.0f);
        union { unsigned long long u; __hip_bfloat16 h[4]; } pk;
        pk.h[0] = __float2bfloat16(lsum[t][0] * inv);
        pk.h[1] = __float2bfloat16(lsum[t][1] * inv);
        pk.h[2] = __float2bfloat16(lsum[t][2] * inv);
        pk.h[3] = __float2bfloat16(lsum[t][3] * inv);
        *reinterpret_cast<unsigned long long*>(proto + (size_t)t * DIM + b * 4) = pk.u;
    }
}

// ---------------- distance via MFMA: -dist = 2*x.p - |x|^2 - |p|^2 --------
// grid (M/32, 2); 256 threads; As 8 KB + Bs 32 KB LDS, XOR-swizzled chunks.
__global__ __launch_bounds__(256) void dist_kernel(
    const float* __restrict__ x, const __hip_bfloat16* __restrict__ proto,
    float* __restrict__ out)
{
    __shared__ unsigned short As[MT][DIM];   // bf16 bits, chunk-swizzled
    __shared__ unsigned short Bs[NT][DIM];
    __shared__ float xn[MT];
    __shared__ float pn[NT];

    const int t  = threadIdx.x;
    const int bm = blockIdx.x;    // 0..255
    const int bn = blockIdx.y;    // 0..1

    if (t < MT) xn[t] = 0.0f;
    if (t < NT) pn[t] = 0.0f;
    __syncthreads();

    // ---- stage A: 32 rows x 16 chunks (chunk = 8 bf16 = 16 B) ----
    const float* xb = x + (size_t)bm * MT * DIM;
    #pragma unroll
    for (int it = 0; it < 2; ++it) {
        int ch = it * 256 + t;            // 0..511
        int r  = ch >> 4, kc = ch & 15;
        float4 v0 = *reinterpret_cast<const float4*>(xb + r * DIM + kc * 8);
        float4 v1 = *reinterpret_cast<const float4*>(xb + r * DIM + kc * 8 + 4);
        float ss = v0.x*v0.x + v0.y*v0.y + v0.z*v0.z + v0.w*v0.w
                 + v1.x*v1.x + v1.y*v1.y + v1.z*v1.z + v1.w*v1.w;
        atomicAdd(&xn[r], ss);
        union { ushort8 u; __hip_bfloat16 h[8]; } pk;
        pk.h[0] = __float2bfloat16(v0.x); pk.h[1] = __float2bfloat16(v0.y);
        pk.h[2] = __float2bfloat16(v0.z); pk.h[3] = __float2bfloat16(v0.w);
        pk.h[4] = __float2bfloat16(v1.x); pk.h[5] = __float2bfloat16(v1.y);
        pk.h[6] = __float2bfloat16(v1.z); pk.h[7] = __float2bfloat16(v1.w);
        *reinterpret_cast<ushort8*>(&As[r][(kc ^ (r & 7)) * 8]) = pk.u;
    }

    // ---- stage B: 128 cols x 16 chunks ----
    const __hip_bfloat16* pb = proto + (size_t)bn * NT * DIM;
    #pragma unroll
    for (int it = 0; it < 8; ++it) {
        int ch = it * 256 + t;            // 0..2047
        int c  = ch >> 4, kc = ch & 15;
        ushort8 w = *reinterpret_cast<const ushort8*>(pb + (size_t)c * DIM + kc * 8);
        const __hip_bfloat16* hw = reinterpret_cast<const __hip_bfloat16*>(&w);
        float ss = 0.0f;
        #pragma unroll
        for (int j = 0; j < 8; ++j) { float f = __bfloat162float(hw[j]); ss += f * f; }
        atomicAdd(&pn[c], ss);
        *reinterpret_cast<ushort8*>(&Bs[c][(kc ^ (c & 7)) * 8]) = w;
    }
    __syncthreads();

    // ---- MFMA: each wave owns 32 cols, all 32 rows ----
    const int wid  = t >> 6;
    const int lane = t & 63;
    const int li = lane & 15, lh = lane >> 4;

    f32x4 acc[2][2] = {};
    #pragma unroll
    for (int s = 0; s < 4; ++s) {
        int chunk = s * 4 + lh;           // 16B chunk index along K
        bf16x8 a[2], b[2];
        #pragma unroll
        for (int mf = 0; mf < 2; ++mf) {
            int r = mf * 16 + li;
            a[mf] = *reinterpret_cast<const bf16x8*>(&As[r][(chunk ^ (r & 7)) * 8]);
        }
        #pragma unroll
        for (int nf = 0; nf < 2; ++nf) {
            int c = wid * 32 + nf * 16 + li;
            b[nf] = *reinterpret_cast<const bf16x8*>(&Bs[c][(chunk ^ (c & 7)) * 8]);
        }
        #pragma unroll
        for (int mf = 0; mf < 2; ++mf)
            #pragma unroll
            for (int nf = 0; nf < 2; ++nf)
                acc[mf][nf] = __builtin_amdgcn_mfma_f32_16x16x32_bf16(
                    a[mf], b[nf], acc[mf][nf], 0, 0, 0);
    }

    // ---- epilogue: out = 2*dot - xn - pn ----
    #pragma unroll
    for (int mf = 0; mf < 2; ++mf) {
        #pragma unroll
        for (int nf = 0; nf < 2; ++nf) {
            int n = wid * 32 + nf * 16 + li;
            #pragma unroll
            for (int r = 0; r < 4; ++r) {
                int m = mf * 16 + lh * 4 + r;
                float val = 2.0f * acc[mf][nf][r] - xn[m] - pn[n];
                out[(size_t)(bm * MT + m) * N_CLASSES + bn * NT + n] = val;
            }
        }
    }
}

extern "C" void kernel_launch(void* const* d_in, const int* in_sizes, int n_in,
                              void* d_out, int out_size, void* d_ws, size_t ws_size,
                              hipStream_t stream) {
    const float* x       = (const float*)d_in[0];   // 8192*128
    const float* support = (const float*)d_in[1];   // 4096*128
    const int*   labels  = (const int*)d_in[2];     // 4096
    float* out = (float*)d_out;                     // 8192*256

    __hip_bfloat16* proto = (__hip_bfloat16*)d_ws;  // 256*128 bf16 = 64 KB

    proto_kernel<<<dim3(DIM / 4), 512, 0, stream>>>(support, labels, proto);
    dist_kernel<<<dim3(M_ROWS / MT, N_CLASSES / NT), 256, 0, stream>>>(x, proto, out);
}

// Round 3
// 94.112 us; speedup vs baseline: 1.0455x; 1.0455x over previous
//
#include <hip/hip_runtime.h>
#include <hip/hip_bf16.h>

#define N_CLASSES 256
#define DIM 128
#define M_ROWS 8192
#define S_ROWS 4096

#define MT 32    // m-rows per block (dist kernel)
#define NT 128   // classes per block (dist kernel)

typedef short  bf16x8  __attribute__((ext_vector_type(8)));
typedef unsigned short ushort8 __attribute__((ext_vector_type(8)));
typedef float  f32x4   __attribute__((ext_vector_type(4)));

// ---------------- prototypes: per-class mean, output bf16 ----------------
// 32 blocks; block b owns dims [4b, 4b+4). LDS-accumulated sums+counts,
// every proto element written exactly once -> no pre-zero, no global atomics.
__global__ __launch_bounds__(512) void proto_kernel(
    const float* __restrict__ support, const int* __restrict__ labels,
    __hip_bfloat16* __restrict__ proto /* [256][128] */)
{
    __shared__ float lsum[N_CLASSES][4];
    __shared__ float lcnt[N_CLASSES];

    const int t = threadIdx.x;        // 0..511
    const int b = blockIdx.x;         // dim-slice 4b..4b+3

    #pragma unroll
    for (int i = t; i < N_CLASSES * 4; i += 512) ((float*)lsum)[i] = 0.0f;
    if (t < N_CLASSES) lcnt[t] = 0.0f;
    __syncthreads();

    #pragma unroll
    for (int it = 0; it < S_ROWS / 512; ++it) {   // 8 iters
        int r = it * 512 + t;
        int lab = labels[r];
        float4 v = *reinterpret_cast<const float4*>(support + (size_t)r * DIM + b * 4);
        atomicAdd(&lsum[lab][0], v.x);
        atomicAdd(&lsum[lab][1], v.y);
        atomicAdd(&lsum[lab][2], v.z);
        atomicAdd(&lsum[lab][3], v.w);
        atomicAdd(&lcnt[lab], 1.0f);
    }
    __syncthreads();

    if (t < N_CLASSES) {
        float inv = 1.0f / fmaxf(lcnt[t], 1.0f);
        union { unsigned long long u; __hip_bfloat16 h[4]; } pk;
        pk.h[0] = __float2bfloat16(lsum[t][0] * inv);
        pk.h[1] = __float2bfloat16(lsum[t][1] * inv);
        pk.h[2] = __float2bfloat16(lsum[t][2] * inv);
        pk.h[3] = __float2bfloat16(lsum[t][3] * inv);
        *reinterpret_cast<unsigned long long*>(proto + (size_t)t * DIM + b * 4) = pk.u;
    }
}

// ---------------- distance via MFMA: -dist = 2*x.p - |x|^2 - |p|^2 --------
// grid (M/32, 2); 256 threads; As 8 KB + Bs 32 KB LDS, XOR-swizzled chunks.
// Row norms reduced via width-16 shfl_xor (the 16 lanes staging one row),
// written once each -- no LDS atomics, no init barrier.
__global__ __launch_bounds__(256) void dist_kernel(
    const float* __restrict__ x, const __hip_bfloat16* __restrict__ proto,
    float* __restrict__ out)
{
    __shared__ unsigned short As[MT][DIM];   // bf16 bits, chunk-swizzled
    __shared__ unsigned short Bs[NT][DIM];
    __shared__ float xn[MT];
    __shared__ float pn[NT];

    const int t  = threadIdx.x;
    const int bm = blockIdx.x;    // 0..255
    const int bn = blockIdx.y;    // 0..1

    // ---- stage A: 32 rows x 16 chunks (chunk = 8 bf16 = 16 B) ----
    const float* xb = x + (size_t)bm * MT * DIM;
    #pragma unroll
    for (int it = 0; it < 2; ++it) {
        int ch = it * 256 + t;            // 0..511
        int r  = ch >> 4, kc = ch & 15;
        float4 v0 = *reinterpret_cast<const float4*>(xb + r * DIM + kc * 8);
        float4 v1 = *reinterpret_cast<const float4*>(xb + r * DIM + kc * 8 + 4);
        float ss = v0.x*v0.x + v0.y*v0.y + v0.z*v0.z + v0.w*v0.w
                 + v1.x*v1.x + v1.y*v1.y + v1.z*v1.z + v1.w*v1.w;
        // width-16 butterfly: the 16 lanes holding row r sum their chunks
        ss += __shfl_xor(ss, 1, 16);
        ss += __shfl_xor(ss, 2, 16);
        ss += __shfl_xor(ss, 4, 16);
        ss += __shfl_xor(ss, 8, 16);
        if (kc == 0) xn[r] = ss;
        union { ushort8 u; __hip_bfloat16 h[8]; } pk;
        pk.h[0] = __float2bfloat16(v0.x); pk.h[1] = __float2bfloat16(v0.y);
        pk.h[2] = __float2bfloat16(v0.z); pk.h[3] = __float2bfloat16(v0.w);
        pk.h[4] = __float2bfloat16(v1.x); pk.h[5] = __float2bfloat16(v1.y);
        pk.h[6] = __float2bfloat16(v1.z); pk.h[7] = __float2bfloat16(v1.w);
        *reinterpret_cast<ushort8*>(&As[r][(kc ^ (r & 7)) * 8]) = pk.u;
    }

    // ---- stage B: 128 cols x 16 chunks ----
    const __hip_bfloat16* pb = proto + (size_t)bn * NT * DIM;
    #pragma unroll
    for (int it = 0; it < 8; ++it) {
        int ch = it * 256 + t;            // 0..2047
        int c  = ch >> 4, kc = ch & 15;
        ushort8 w = *reinterpret_cast<const ushort8*>(pb + (size_t)c * DIM + kc * 8);
        const __hip_bfloat16* hw = reinterpret_cast<const __hip_bfloat16*>(&w);
        float ss = 0.0f;
        #pragma unroll
        for (int j = 0; j < 8; ++j) { float f = __bfloat162float(hw[j]); ss += f * f; }
        ss += __shfl_xor(ss, 1, 16);
        ss += __shfl_xor(ss, 2, 16);
        ss += __shfl_xor(ss, 4, 16);
        ss += __shfl_xor(ss, 8, 16);
        if (kc == 0) pn[c] = ss;
        *reinterpret_cast<ushort8*>(&Bs[c][(kc ^ (c & 7)) * 8]) = w;
    }
    __syncthreads();

    // ---- MFMA: each wave owns 32 cols, all 32 rows ----
    const int wid  = t >> 6;
    const int lane = t & 63;
    const int li = lane & 15, lh = lane >> 4;

    f32x4 acc[2][2] = {};
    #pragma unroll
    for (int s = 0; s < 4; ++s) {
        int chunk = s * 4 + lh;           // 16B chunk index along K
        bf16x8 a[2], b[2];
        #pragma unroll
        for (int mf = 0; mf < 2; ++mf) {
            int r = mf * 16 + li;
            a[mf] = *reinterpret_cast<const bf16x8*>(&As[r][(chunk ^ (r & 7)) * 8]);
        }
        #pragma unroll
        for (int nf = 0; nf < 2; ++nf) {
            int c = wid * 32 + nf * 16 + li;
            b[nf] = *reinterpret_cast<const bf16x8*>(&Bs[c][(chunk ^ (c & 7)) * 8]);
        }
        #pragma unroll
        for (int mf = 0; mf < 2; ++mf)
            #pragma unroll
            for (int nf = 0; nf < 2; ++nf)
                acc[mf][nf] = __builtin_amdgcn_mfma_f32_16x16x32_bf16(
                    a[mf], b[nf], acc[mf][nf], 0, 0, 0);
    }

    // ---- epilogue: out = 2*dot - xn - pn ----
    #pragma unroll
    for (int mf = 0; mf < 2; ++mf) {
        #pragma unroll
        for (int nf = 0; nf < 2; ++nf) {
            int n = wid * 32 + nf * 16 + li;
            #pragma unroll
            for (int r = 0; r < 4; ++r) {
                int m = mf * 16 + lh * 4 + r;
                float val = 2.0f * acc[mf][nf][r] - xn[m] - pn[n];
                out[(size_t)(bm * MT + m) * N_CLASSES + bn * NT + n] = val;
            }
        }
    }
}

extern "C" void kernel_launch(void* const* d_in, const int* in_sizes, int n_in,
                              void* d_out, int out_size, void* d_ws, size_t ws_size,
                              hipStream_t stream) {
    const float* x       = (const float*)d_in[0];   // 8192*128
    const float* support = (const float*)d_in[1];   // 4096*128
    const int*   labels  = (const int*)d_in[2];     // 4096
    float* out = (float*)d_out;                     // 8192*256

    __hip_bfloat16* proto = (__hip_bfloat16*)d_ws;  // 256*128 bf16 = 64 KB

    proto_kernel<<<dim3(DIM / 4), 512, 0, stream>>>(support, labels, proto);
    dist_kernel<<<dim3(M_ROWS / MT, N_CLASSES / NT), 256, 0, stream>>>(x, proto, out);
}